// Round 1
// baseline (33.990 us; speedup 1.0000x reference)
//
#include <hip/hip_runtime.h>

// AxonLIFNode: sequential LIF + axon-current recurrence over T.
//   mem   = mem + (x_t + V_RESET - mem) / TAU        (V_RESET=0, TAU=2)
//   spike = (mem - V_TH > 0) ? 1 : 0                 (V_TH=1)
//   mem   = spike ? V_RESET : mem
//   out_i = out_i * sigmoid(w) + spike
// Outputs: spikes [B,T,N], i_pot [B,T,N], concatenated flat.
//
// B=64, T=64, N=4096 (fixed by setup_inputs). One thread per (b, n/4),
// float4 vectorized; consecutive threads -> consecutive n -> coalesced.

#define LIF_B 64
#define LIF_T 64
#define LIF_N 4096
#define LIF_N4 (LIF_N / 4)

__global__ __launch_bounds__(256) void axon_lif_kernel(
    const float4* __restrict__ X,       // [B, T, N/4]
    const float* __restrict__ wp,       // scalar
    float4* __restrict__ out_spike,     // [B, T, N/4]
    float4* __restrict__ out_ipot)      // [B, T, N/4]
{
    const int idx = blockIdx.x * blockDim.x + threadIdx.x;  // over B * N4
    const int b  = idx >> 10;           // / LIF_N4 (1024)
    const int n4 = idx & (LIF_N4 - 1);

    const float w = wp[0];
    const float inv_tau = 1.0f / (1.0f + expf(-w));   // sigmoid(w)

    float4 mem = make_float4(0.f, 0.f, 0.f, 0.f);
    float4 oi  = make_float4(0.f, 0.f, 0.f, 0.f);

    const size_t base = (size_t)b * LIF_T * LIF_N4 + n4;

#pragma unroll 8
    for (int t = 0; t < LIF_T; ++t) {
        const size_t a = base + (size_t)t * LIF_N4;
        const float4 x = X[a];
        float4 sp;

        // component-wise LIF step, in the reference's arithmetic order
#define LIF_STEP(c)                                            \
        {                                                      \
            mem.c = mem.c + (x.c + 0.0f - mem.c) / 2.0f;       \
            const float d = mem.c - 1.0f;                      \
            const float s = (d > 0.0f) ? 1.0f : 0.0f;          \
            mem.c = (s > 0.0f) ? 0.0f : mem.c;                 \
            oi.c = oi.c * inv_tau + s;                         \
            sp.c = s;                                          \
        }
        LIF_STEP(x)
        LIF_STEP(y)
        LIF_STEP(z)
        LIF_STEP(w)
#undef LIF_STEP

        out_spike[a] = sp;
        out_ipot[a]  = oi;
    }
}

extern "C" void kernel_launch(void* const* d_in, const int* in_sizes, int n_in,
                              void* d_out, int out_size, void* d_ws, size_t ws_size,
                              hipStream_t stream) {
    const float* X = (const float*)d_in[0];
    const float* w = (const float*)d_in[1];
    float* out = (float*)d_out;

    float* spikes = out;                                  // [B,T,N]
    float* ipot   = out + (size_t)LIF_B * LIF_T * LIF_N;  // [B,T,N]

    const int total = LIF_B * LIF_N4;   // 65536 threads
    const int block = 256;
    const int grid  = (total + block - 1) / block;

    axon_lif_kernel<<<grid, block, 0, stream>>>(
        (const float4*)X, w, (float4*)spikes, (float4*)ipot);
}